// Round 3
// baseline (403.765 us; speedup 1.0000x reference)
//
#include <hip/hip_runtime.h>

// textPCNN fused (R8): R7 landed 2 blocks/CU but all pipes sit at ~37%:
// MFMA floor is 79us (9.96e6 mfma x 19.4cy/SIMD), B-L2 74us, yet dur=200us.
// Diagnosis: 16 waves/CU run lockstep from the same barrier -> all 4
// waves/SIMD issue their B-loads together and wait ~300-500cy together;
// no wave has MFMAs ready to cover latency. Register prefetch impossible
// (56V + 64 acc = 120/128 unified budget; +16 regs -> 1 block/CU).
// Fix (register-free): stagger each wave's K-loop start iteration
// (ks0 = (wv*5 + bid%19) % 38, wrap over all 38; fp32 sum order is
// tolerance-irrelevant) so load-waits and MFMA bursts interleave across
// waves. Also: pcnn_out reads outwT per sentence (333MB L2) -> 8
// sentences/block with weight row in 24 regs (42MB).

#define XSTRIDE 424     // LDS x-row stride in bf16 elems (848 B = 53 short8)
#define LPV 126
#define NC 53

typedef __attribute__((ext_vector_type(8))) short short8;
typedef __attribute__((ext_vector_type(4))) float floatx4;

__device__ __forceinline__ unsigned short f2bf_rne(float x) {
    unsigned u = __float_as_uint(x);
    u += 0x7fffu + ((u >> 16) & 1u);   // round-to-nearest-even (inputs finite)
    return (unsigned short)(u >> 16);
}

// prep: conv_w fp32 [512][3*400] -> bf16 frag-packed convwb2:
//   flat = (((ftile*38+ks)*4+kq)*16+col)*8 + e ; k=ks*32+kq*8+e, f=ftile*16+col
//   k>=1200 -> 0 (zero K tail, uniform 38-iter K-loop)
// plus out_w [1536][53] -> outwT [53][1536] fp32 (coalesced epilogue reads).
__global__ void __launch_bounds__(1024)
prep(const float* __restrict__ convw, const float* __restrict__ outw,
     unsigned short* __restrict__ convwb2, float* __restrict__ outwT) {
    int i = blockIdx.x * 1024 + threadIdx.x;
    if (i < 622592) {
        int e = i & 7, col = (i >> 3) & 15, kq = (i >> 7) & 3;
        int rest = i >> 9;
        int ks = rest % 38, ftile = rest / 38;
        int k = ks * 32 + kq * 8 + e, f = ftile * 16 + col;
        convwb2[i] = (k < 1200) ? f2bf_rne(convw[f * 1200 + k])
                                : (unsigned short)0;
    } else {
        int i2 = i - 622592;
        if (i2 < 81408) {                  // 53*1536
            int c = i2 / 1536, j = i2 - c * 1536;
            outwT[i2] = outw[j * 53 + c];
        }
    }
}

// kernel 2: one block per (sentence, t-half). Gather 67 x-rows -> LDS,
// conv GEMM 8 waves x (64t x 64f) with staggered K-start, pool raw 3-seg
// max, write to ws pfe.
extern "C" __global__ void __launch_bounds__(512, 4)
pcnn_half(const int* __restrict__ tokens, const int* __restrict__ pf1,
          const int* __restrict__ pf2, const int* __restrict__ epos,
          const float* __restrict__ wordvec,
          const float* __restrict__ pf1e,
          const float* __restrict__ pf2e,
          const unsigned short* __restrict__ convwb2,  // frag-packed bf16 in ws
          float* __restrict__ pfe)                     // [1024][2][1536] raw max
{
    extern __shared__ char smem[];
    unsigned short* xl = (unsigned short*)smem;        // 67*424 ush = 56816 B
    int* idx = (int*)(smem + 56816);                   // 3*67 ints (816 B pad)

    const int bid = blockIdx.x;
    const int n   = bid >> 1;
    const int wr  = bid & 1;        // t-half: global t in [64wr, 64wr+64)
    const int r0  = wr * 64;
    const int nreal = wr ? 64 : 67; // real x-rows this block stages

    const int tid  = threadIdx.x;
    const int lane = tid & 63;
    const int wv   = tid >> 6;      // 0..7 : f in [64wv, 64wv+64)

    if (tid < nreal) {
        int base = n * 128 + r0 + tid;
        idx[tid]       = tokens[base];
        idx[67 + tid]  = pf1[base];
        idx[134 + tid] = pf2[base];
    }
    if (wr) {   // local rows 64..66 are past end of sentence: zero them
        const short8 z8 = {0, 0, 0, 0, 0, 0, 0, 0};
        short8* dst = (short8*)xl;                     // 53 short8 per row
        for (int i = tid; i < 159; i += 512) {
            int row = 64 + i / 53, c = i % 53;
            dst[row * 53 + c] = z8;
        }
    }
    __syncthreads();

    // ---- gather + fp32->bf16 (float4 word loads; rows 16B-aligned) ----
    {
        const float4* wv4 = (const float4*)wordvec;    // 75 float4 per row
        const float2* p12 = (const float2*)pf1e;       // 25 float2 per row
        const float2* p22 = (const float2*)pf2e;
        #pragma unroll 4
        for (int i = tid; i < nreal * 75; i += 512) {  // word part
            int row = i / 75, c = i - row * 75;
            float4 v = wv4[(long)idx[row] * 75 + c];
            *(ushort4*)(xl + row * XSTRIDE + 4 * c) =
                make_ushort4(f2bf_rne(v.x), f2bf_rne(v.y),
                             f2bf_rne(v.z), f2bf_rne(v.w));
        }
        #pragma unroll 4
        for (int i = tid; i < nreal * 25; i += 512) {  // pf1 + pf2 parts
            int row = i / 25, c = i - row * 25;
            float2 v = p12[idx[67 + row] * 25 + c];
            *(ushort2*)(xl + row * XSTRIDE + 300 + 2 * c) =
                make_ushort2(f2bf_rne(v.x), f2bf_rne(v.y));
            float2 w = p22[idx[134 + row] * 25 + c];
            *(ushort2*)(xl + row * XSTRIDE + 350 + 2 * c) =
                make_ushort2(f2bf_rne(w.x), f2bf_rne(w.y));
        }
    }
    __syncthreads();

    // ---- conv GEMM: wave wv owns local t[0,64) x f[64wv, 64wv+64) ----
    // A[t][k] = xl[t + k/400][k%400]; B frag-packed (1KB coalesced wave-loads).
    // Staggered K-start (acc order irrelevant): waves de-phase so each SIMD
    // always has an MFMA-ready wave while others wait on B.
    const int col = lane & 15;   // A row-in-tile / B f-in-tile / C col
    const int kq  = lane >> 4;   // k-quad: k offset 8*kq; C row = 4*kq + r

    const floatx4 fz = {0.f, 0.f, 0.f, 0.f};
    floatx4 acc[4][4];   // [mt][jt]
    #pragma unroll
    for (int mt = 0; mt < 4; ++mt)
        #pragma unroll
        for (int jt = 0; jt < 4; ++jt) acc[mt][jt] = fz;

    const int ks0 = (wv * 5 + bid % 19) % 38;
    const int kb  = ks0 * 32 + kq * 8;           // this lane's starting k
    int ck   = kb % 400;                         // k mod 400 for this lane
    int aoff = (col + kb / 400) * XSTRIDE + ck;
    const unsigned short* bwv = convwb2 + (wv * 4 * 38) * 512 + lane * 8;

    int ks = ks0;
    #pragma unroll 1
    for (int i = 0; i < 38; ++i) {
        short8 b[4], a[4];
        #pragma unroll
        for (int jt = 0; jt < 4; ++jt)
            b[jt] = *(const short8*)(bwv + (jt * 38 + ks) * 512);
        #pragma unroll
        for (int mt = 0; mt < 4; ++mt)
            a[mt] = *(const short8*)(xl + aoff + mt * (16 * XSTRIDE));
        __builtin_amdgcn_s_setprio(1);
        #pragma unroll
        for (int mt = 0; mt < 4; ++mt)
            #pragma unroll
            for (int jt = 0; jt < 4; ++jt)
                acc[mt][jt] = __builtin_amdgcn_mfma_f32_16x16x32_bf16(
                    a[mt], b[jt], acc[mt][jt], 0, 0, 0);
        __builtin_amdgcn_s_setprio(0);
        ++ks; ck += 32; aoff += 32;
        if (ck >= 400) { ck -= 400; aoff += XSTRIDE - 400; }
        if (ks == 38) { ks = 0; ck = kq * 8; aoff = col * XSTRIDE + ck; }
    }

    // ---- pool raw acc over 3 segments (this half's t-range), write ws ----
    const int p1 = epos[2 * n], p2 = epos[2 * n + 1];
    float* pf_out = pfe + (n * 2 + wr) * 1536;
    #pragma unroll
    for (int jt = 0; jt < 4; ++jt) {
        float m0 = -1e30f, m1 = -1e30f, m2 = -1e30f;
        #pragma unroll
        for (int mt = 0; mt < 4; ++mt) {
            #pragma unroll
            for (int r = 0; r < 4; ++r) {
                int gt = r0 + mt * 16 + kq * 4 + r;   // global t (C/D row map)
                float v = acc[mt][jt][r];
                if (gt < LPV) {
                    if (gt <= p1) m0 = fmaxf(m0, v);
                    if (gt >= p1 && gt <= p2) m1 = fmaxf(m1, v);
                    if (gt >= p2) m2 = fmaxf(m2, v);
                }
            }
        }
        // lanes sharing col differ in kq (xor 16, 32): reduce t-coverage
        m0 = fmaxf(m0, __shfl_xor(m0, 16)); m0 = fmaxf(m0, __shfl_xor(m0, 32));
        m1 = fmaxf(m1, __shfl_xor(m1, 16)); m1 = fmaxf(m1, __shfl_xor(m1, 32));
        m2 = fmaxf(m2, __shfl_xor(m2, 16)); m2 = fmaxf(m2, __shfl_xor(m2, 32));
        if (kq == 0) {
            int f = wv * 64 + jt * 16 + col;
            pf_out[3 * f + 0] = m0;    // raw max; tanh after cross-half combine
            pf_out[3 * f + 1] = m1;
            pf_out[3 * f + 2] = m2;
        }
    }
}

// kernel 3: combine t-halves, +bias, tanh, out GEMM. 8 sentences per block;
// out_w row held in 24 regs per lane -> outwT L2 traffic 333MB -> 42MB.
extern "C" __global__ void __launch_bounds__(256)
pcnn_out(const float* __restrict__ pfe, const float* __restrict__ convb,
         const float* __restrict__ outwT,            // [53][1536] fp32 in ws
         const float* __restrict__ outb, float* __restrict__ out)
{
    __shared__ float feat[8 * 1536];
    const int n0 = blockIdx.x * 8;
    const int tid = threadIdx.x;

    #pragma unroll 1
    for (int nl = 0; nl < 8; ++nl) {
        const float* pa = pfe + (n0 + nl) * 3072;
        for (int j = tid; j < 1536; j += 256) {
            float v = fmaxf(pa[j], pa[1536 + j]);
            // tanh monotonic: max(tanh(x+b)) == tanh(max(x)+b); segs nonempty
            feat[nl * 1536 + j] = tanhf(v + convb[j / 3]);
        }
    }
    __syncthreads();

    const int lane = tid & 63;
    const int wv   = tid >> 6;     // 0..3
    for (int cc = wv; cc < NC; cc += 4) {
        float wrow[24];
        const float* wp = outwT + cc * 1536 + lane;
        #pragma unroll
        for (int u = 0; u < 24; ++u) wrow[u] = wp[u * 64];
        #pragma unroll 1
        for (int nl = 0; nl < 8; ++nl) {
            const float* fp = feat + nl * 1536 + lane;
            float s = 0.f;
            #pragma unroll
            for (int u = 0; u < 24; ++u) s += fp[u * 64] * wrow[u];
            s += __shfl_xor(s, 32); s += __shfl_xor(s, 16);
            s += __shfl_xor(s, 8);  s += __shfl_xor(s, 4);
            s += __shfl_xor(s, 2);  s += __shfl_xor(s, 1);
            if (lane == 0) out[(n0 + nl) * 53 + cc] = s + outb[cc];
        }
    }
}

extern "C" void kernel_launch(void* const* d_in, const int* in_sizes, int n_in,
                              void* d_out, int out_size, void* d_ws, size_t ws_size,
                              hipStream_t stream) {
    (void)in_sizes; (void)n_in; (void)ws_size; (void)out_size;
    const int* tokens = (const int*)d_in[0];
    const int* pf1    = (const int*)d_in[1];
    const int* pf2    = (const int*)d_in[2];
    const int* epos   = (const int*)d_in[3];
    const float* wordvec = (const float*)d_in[4];
    const float* pf1e    = (const float*)d_in[5];
    const float* pf2e    = (const float*)d_in[6];
    const float* convw   = (const float*)d_in[7];
    const float* convb   = (const float*)d_in[8];
    const float* outw    = (const float*)d_in[9];
    const float* outb    = (const float*)d_in[10];
    float* out = (float*)d_out;

    unsigned short* convwb2 = (unsigned short*)d_ws;       // 1,245,184 B
    float* outwT = (float*)((char*)d_ws + 1245184);        // 325,632 B
    float* pfe   = (float*)((char*)d_ws + 1570816);        // 1024*2*1536 f = 12.6 MB

    prep<<<dim3(688), dim3(1024), 0, stream>>>(convw, outw, convwb2, outwT);

    const size_t lds_bytes = 56816 + 816;                  // 57,632 B -> 2 blocks/CU
    pcnn_half<<<dim3(2048), dim3(512), lds_bytes, stream>>>(
        tokens, pf1, pf2, epos, wordvec, pf1e, pf2e, convwb2, pfe);

    pcnn_out<<<dim3(128), dim3(256), 0, stream>>>(pfe, convb, outwT, outb, out);
}

// Round 4
// 357.253 us; speedup vs baseline: 1.1302x; 1.1302x over previous
//
#include <hip/hip_runtime.h>

// textPCNN fused (R9): R8 post-mortem — K-index stagger doesn't de-phase
// waves in TIME (same instruction cadence from same barrier -> synchronized
// vmcnt stalls; MfmaUtil 41% == single-wave duty cycle). Fix: per-wave
// register double-buffer of B (unroll-2 K-loop, load ks+1 before MFMA of ks):
// ~400cy L2 latency hides under 310cy own-wave MFMA. Budget: b0/b1/a 48 +
// acc 64 + addr ~12 = ~124 <= 128 -> keeps 4 waves/SIMD, 2 blocks/CU.
// pcnn_out: R8's 8-sentence/128-block version starved the grid (~75us vs
// ~20us); its L2-traffic "win" was worth only ~10us at 34TB/s. Reverted to
// R7 form (1024 blocks, 1 sentence each).

#define XSTRIDE 424     // LDS x-row stride in bf16 elems (848 B = 53 short8)
#define LPV 126
#define NC 53

typedef __attribute__((ext_vector_type(8))) short short8;
typedef __attribute__((ext_vector_type(4))) float floatx4;

__device__ __forceinline__ unsigned short f2bf_rne(float x) {
    unsigned u = __float_as_uint(x);
    u += 0x7fffu + ((u >> 16) & 1u);   // round-to-nearest-even (inputs finite)
    return (unsigned short)(u >> 16);
}

// prep: conv_w fp32 [512][3*400] -> bf16 frag-packed convwb2:
//   flat = (((ftile*38+ks)*4+kq)*16+col)*8 + e ; k=ks*32+kq*8+e, f=ftile*16+col
//   k>=1200 -> 0 (zero K tail, uniform 38-iter K-loop)
// plus out_w [1536][53] -> outwT [53][1536] fp32 (coalesced epilogue reads).
__global__ void __launch_bounds__(1024)
prep(const float* __restrict__ convw, const float* __restrict__ outw,
     unsigned short* __restrict__ convwb2, float* __restrict__ outwT) {
    int i = blockIdx.x * 1024 + threadIdx.x;
    if (i < 622592) {
        int e = i & 7, col = (i >> 3) & 15, kq = (i >> 7) & 3;
        int rest = i >> 9;
        int ks = rest % 38, ftile = rest / 38;
        int k = ks * 32 + kq * 8 + e, f = ftile * 16 + col;
        convwb2[i] = (k < 1200) ? f2bf_rne(convw[f * 1200 + k])
                                : (unsigned short)0;
    } else {
        int i2 = i - 622592;
        if (i2 < 81408) {                  // 53*1536
            int c = i2 / 1536, j = i2 - c * 1536;
            outwT[i2] = outw[j * 53 + c];
        }
    }
}

// kernel 2: one block per (sentence, t-half). Gather 67 x-rows -> LDS,
// conv GEMM 8 waves x (64t x 64f) with register-double-buffered B,
// pool raw 3-seg max, write to ws pfe.
extern "C" __global__ void __launch_bounds__(512, 4)
pcnn_half(const int* __restrict__ tokens, const int* __restrict__ pf1,
          const int* __restrict__ pf2, const int* __restrict__ epos,
          const float* __restrict__ wordvec,
          const float* __restrict__ pf1e,
          const float* __restrict__ pf2e,
          const unsigned short* __restrict__ convwb2,  // frag-packed bf16 in ws
          float* __restrict__ pfe)                     // [1024][2][1536] raw max
{
    extern __shared__ char smem[];
    unsigned short* xl = (unsigned short*)smem;        // 67*424 ush = 56816 B
    int* idx = (int*)(smem + 56816);                   // 3*67 ints (816 B pad)

    const int bid = blockIdx.x;
    const int n   = bid >> 1;
    const int wr  = bid & 1;        // t-half: global t in [64wr, 64wr+64)
    const int r0  = wr * 64;
    const int nreal = wr ? 64 : 67; // real x-rows this block stages

    const int tid  = threadIdx.x;
    const int lane = tid & 63;
    const int wv   = tid >> 6;      // 0..7 : f in [64wv, 64wv+64)

    if (tid < nreal) {
        int base = n * 128 + r0 + tid;
        idx[tid]       = tokens[base];
        idx[67 + tid]  = pf1[base];
        idx[134 + tid] = pf2[base];
    }
    if (wr) {   // local rows 64..66 are past end of sentence: zero them
        const short8 z8 = {0, 0, 0, 0, 0, 0, 0, 0};
        short8* dst = (short8*)xl;                     // 53 short8 per row
        for (int i = tid; i < 159; i += 512) {
            int row = 64 + i / 53, c = i % 53;
            dst[row * 53 + c] = z8;
        }
    }
    __syncthreads();

    // ---- gather + fp32->bf16 (float4 word loads; rows 16B-aligned) ----
    {
        const float4* wv4 = (const float4*)wordvec;    // 75 float4 per row
        const float2* p12 = (const float2*)pf1e;       // 25 float2 per row
        const float2* p22 = (const float2*)pf2e;
        #pragma unroll 4
        for (int i = tid; i < nreal * 75; i += 512) {  // word part
            int row = i / 75, c = i - row * 75;
            float4 v = wv4[(long)idx[row] * 75 + c];
            *(ushort4*)(xl + row * XSTRIDE + 4 * c) =
                make_ushort4(f2bf_rne(v.x), f2bf_rne(v.y),
                             f2bf_rne(v.z), f2bf_rne(v.w));
        }
        #pragma unroll 4
        for (int i = tid; i < nreal * 25; i += 512) {  // pf1 + pf2 parts
            int row = i / 25, c = i - row * 25;
            float2 v = p12[idx[67 + row] * 25 + c];
            *(ushort2*)(xl + row * XSTRIDE + 300 + 2 * c) =
                make_ushort2(f2bf_rne(v.x), f2bf_rne(v.y));
            float2 w = p22[idx[134 + row] * 25 + c];
            *(ushort2*)(xl + row * XSTRIDE + 350 + 2 * c) =
                make_ushort2(f2bf_rne(w.x), f2bf_rne(w.y));
        }
    }
    __syncthreads();

    // ---- conv GEMM: wave wv owns local t[0,64) x f[64wv, 64wv+64) ----
    // A[t][k] = xl[t + k/400][k%400]; B frag-packed (1KB coalesced wave-loads),
    // register-double-buffered one K-step ahead (unroll-2, no copies).
    const int col = lane & 15;   // A row-in-tile / B f-in-tile / C col
    const int kq  = lane >> 4;   // k-quad: k offset 8*kq; C row = 4*kq + r

    const floatx4 fz = {0.f, 0.f, 0.f, 0.f};
    floatx4 acc[4][4];   // [mt][jt]
    #pragma unroll
    for (int mt = 0; mt < 4; ++mt)
        #pragma unroll
        for (int jt = 0; jt < 4; ++jt) acc[mt][jt] = fz;

    int ck   = kq * 8;                           // k mod 400 for this lane
    int aoff = col * XSTRIDE + kq * 8;
    const unsigned short* bwv = convwb2 + (wv * 4 * 38) * 512 + lane * 8;

    short8 b0[4], b1[4];
    #pragma unroll
    for (int jt = 0; jt < 4; ++jt)               // prologue: ks=0
        b0[jt] = *(const short8*)(bwv + (jt * 38) * 512);

    #pragma unroll 1
    for (int ks = 0; ks < 38; ks += 2) {         // 19 iterations, 2 K-steps each
        short8 a[4];
        // prefetch ks+1 into b1 (always valid: ks+1 <= 37)
        #pragma unroll
        for (int jt = 0; jt < 4; ++jt)
            b1[jt] = *(const short8*)(bwv + (jt * 38 + ks + 1) * 512);
        #pragma unroll
        for (int mt = 0; mt < 4; ++mt)
            a[mt] = *(const short8*)(xl + aoff + mt * (16 * XSTRIDE));
        __builtin_amdgcn_s_setprio(1);
        #pragma unroll
        for (int mt = 0; mt < 4; ++mt)
            #pragma unroll
            for (int jt = 0; jt < 4; ++jt)
                acc[mt][jt] = __builtin_amdgcn_mfma_f32_16x16x32_bf16(
                    a[mt], b0[jt], acc[mt][jt], 0, 0, 0);
        __builtin_amdgcn_s_setprio(0);
        ck += 32; aoff += 32;
        if (ck >= 400) { ck -= 400; aoff += XSTRIDE - 400; }

        // prefetch ks+2 into b0 (guard final pair)
        if (ks + 2 < 38) {
            #pragma unroll
            for (int jt = 0; jt < 4; ++jt)
                b0[jt] = *(const short8*)(bwv + (jt * 38 + ks + 2) * 512);
        }
        #pragma unroll
        for (int mt = 0; mt < 4; ++mt)
            a[mt] = *(const short8*)(xl + aoff + mt * (16 * XSTRIDE));
        __builtin_amdgcn_s_setprio(1);
        #pragma unroll
        for (int mt = 0; mt < 4; ++mt)
            #pragma unroll
            for (int jt = 0; jt < 4; ++jt)
                acc[mt][jt] = __builtin_amdgcn_mfma_f32_16x16x32_bf16(
                    a[mt], b1[jt], acc[mt][jt], 0, 0, 0);
        __builtin_amdgcn_s_setprio(0);
        ck += 32; aoff += 32;
        if (ck >= 400) { ck -= 400; aoff += XSTRIDE - 400; }
    }

    // ---- pool raw acc over 3 segments (this half's t-range), write ws ----
    const int p1 = epos[2 * n], p2 = epos[2 * n + 1];
    float* pf_out = pfe + (n * 2 + wr) * 1536;
    #pragma unroll
    for (int jt = 0; jt < 4; ++jt) {
        float m0 = -1e30f, m1 = -1e30f, m2 = -1e30f;
        #pragma unroll
        for (int mt = 0; mt < 4; ++mt) {
            #pragma unroll
            for (int r = 0; r < 4; ++r) {
                int gt = r0 + mt * 16 + kq * 4 + r;   // global t (C/D row map)
                float v = acc[mt][jt][r];
                if (gt < LPV) {
                    if (gt <= p1) m0 = fmaxf(m0, v);
                    if (gt >= p1 && gt <= p2) m1 = fmaxf(m1, v);
                    if (gt >= p2) m2 = fmaxf(m2, v);
                }
            }
        }
        // lanes sharing col differ in kq (xor 16, 32): reduce t-coverage
        m0 = fmaxf(m0, __shfl_xor(m0, 16)); m0 = fmaxf(m0, __shfl_xor(m0, 32));
        m1 = fmaxf(m1, __shfl_xor(m1, 16)); m1 = fmaxf(m1, __shfl_xor(m1, 32));
        m2 = fmaxf(m2, __shfl_xor(m2, 16)); m2 = fmaxf(m2, __shfl_xor(m2, 32));
        if (kq == 0) {
            int f = wv * 64 + jt * 16 + col;
            pf_out[3 * f + 0] = m0;    // raw max; tanh after cross-half combine
            pf_out[3 * f + 1] = m1;
            pf_out[3 * f + 2] = m2;
        }
    }
}

// kernel 3: combine t-halves, +bias, tanh, out GEMM. One block per sentence.
// (R7 form: 1024 blocks keeps grid saturated; outwT L2 re-reads cost ~10us
// aggregate at 34 TB/s — cheaper than starving the grid.)
extern "C" __global__ void __launch_bounds__(256)
pcnn_out(const float* __restrict__ pfe, const float* __restrict__ convb,
         const float* __restrict__ outwT,            // [53][1536] fp32 in ws
         const float* __restrict__ outb, float* __restrict__ out)
{
    __shared__ float feat[1536];
    const int n = blockIdx.x;
    const int tid = threadIdx.x;
    const float* pa = pfe + n * 3072;
    const float* pb = pa + 1536;

    for (int i = tid; i < 1536; i += 256) {
        float v = fmaxf(pa[i], pb[i]);
        // tanh monotonic: max(tanh(x+b)) == tanh(max(x)+b); segs nonempty
        feat[i] = tanhf(v + convb[i / 3]);
    }
    __syncthreads();

    const int lane = tid & 63;
    const int wv   = tid >> 6;     // 0..3
    for (int cc = wv; cc < NC; cc += 4) {
        const float* wrow = outwT + cc * 1536;
        float s = 0.f;
        #pragma unroll 4
        for (int jj = lane; jj < 1536; jj += 64)
            s += feat[jj] * wrow[jj];
        s += __shfl_xor(s, 32); s += __shfl_xor(s, 16);
        s += __shfl_xor(s, 8);  s += __shfl_xor(s, 4);
        s += __shfl_xor(s, 2);  s += __shfl_xor(s, 1);
        if (lane == 0) out[n * 53 + cc] = s + outb[cc];
    }
}

extern "C" void kernel_launch(void* const* d_in, const int* in_sizes, int n_in,
                              void* d_out, int out_size, void* d_ws, size_t ws_size,
                              hipStream_t stream) {
    (void)in_sizes; (void)n_in; (void)ws_size; (void)out_size;
    const int* tokens = (const int*)d_in[0];
    const int* pf1    = (const int*)d_in[1];
    const int* pf2    = (const int*)d_in[2];
    const int* epos   = (const int*)d_in[3];
    const float* wordvec = (const float*)d_in[4];
    const float* pf1e    = (const float*)d_in[5];
    const float* pf2e    = (const float*)d_in[6];
    const float* convw   = (const float*)d_in[7];
    const float* convb   = (const float*)d_in[8];
    const float* outw    = (const float*)d_in[9];
    const float* outb    = (const float*)d_in[10];
    float* out = (float*)d_out;

    unsigned short* convwb2 = (unsigned short*)d_ws;       // 1,245,184 B
    float* outwT = (float*)((char*)d_ws + 1245184);        // 325,632 B
    float* pfe   = (float*)((char*)d_ws + 1570816);        // 1024*2*1536 f = 12.6 MB

    prep<<<dim3(688), dim3(1024), 0, stream>>>(convw, outw, convwb2, outwT);

    const size_t lds_bytes = 56816 + 816;                  // 57,632 B -> 2 blocks/CU
    pcnn_half<<<dim3(2048), dim3(512), lds_bytes, stream>>>(
        tokens, pf1, pf2, epos, wordvec, pf1e, pf2e, convwb2, pfe);

    pcnn_out<<<dim3(1024), dim3(256), 0, stream>>>(pfe, convb, outwT, outb, out);
}